// Round 16
// baseline (220.898 us; speedup 1.0000x reference)
//
#include <hip/hip_runtime.h>

typedef __attribute__((ext_vector_type(8))) short bf16x8;
typedef __attribute__((ext_vector_type(4))) float f32x4;

#define B_N 8192
#define D_N 256
#define K_N 64

__device__ __forceinline__ unsigned short bf16_rne(float f) {
  unsigned u = __builtin_bit_cast(unsigned, f);
  u += 0x7fffu + ((u >> 16) & 1u);
  return (unsigned short)(u >> 16);
}
__device__ __forceinline__ float bf16_f32(unsigned short h) {
  return __builtin_bit_cast(float, (unsigned)h << 16);
}

// DMA 16B/lane global->LDS. LDS dest: wave-uniform base + lane*16 (linear).
__device__ __forceinline__ void gload_lds16(const void* g, void* l) {
  __builtin_amdgcn_global_load_lds(
      (const __attribute__((address_space(1))) unsigned int*)g,
      (__attribute__((address_space(3))) unsigned int*)l, 16, 0, 0);
}

// One-time f32 -> bf16 (hi) + bf16 (residual lo) split (for X).
__global__ void convert_kernel(const float* __restrict__ src,
                               ushort* __restrict__ hi, ushort* __restrict__ lo,
                               int n4) {
  int idx = blockIdx.x * blockDim.x + threadIdx.x;
  int stride = gridDim.x * blockDim.x;
  for (int i = idx; i < n4; i += stride) {
    float4 v = ((const float4*)src)[i];
    ushort4 h, l;
    h.x = bf16_rne(v.x); l.x = bf16_rne(v.x - bf16_f32(h.x));
    h.y = bf16_rne(v.y); l.y = bf16_rne(v.y - bf16_f32(h.y));
    h.z = bf16_rne(v.z); l.z = bf16_rne(v.z - bf16_f32(h.z));
    h.w = bf16_rne(v.w); l.w = bf16_rne(v.w - bf16_f32(h.w));
    ((ushort4*)hi)[i] = h;
    ((ushort4*)lo)[i] = l;
  }
}

// Symmetrize-and-fold: x^T S x == x^T Sym x (Sym=(S+S^T)/2) EXACTLY for any
// S. T[d][e] = Sym (same 64-block), 2*Sym (e-block > d-block). LDS
// tile-transpose (R15): both 64x64 tiles load coalesced into padded LDS;
// symmetrize reads LDS. Same adds, same order, same wgt -> bitwise-same T.
__global__ void convert_T_kernel(const float* __restrict__ Sigma,
                                 ushort* __restrict__ Th,
                                 ushort* __restrict__ Tl) {
  const int dtab[10] = {0, 0, 0, 0, 1, 1, 1, 2, 2, 3};
  const int etab[10] = {0, 1, 2, 3, 1, 2, 3, 2, 3, 3};
  __shared__ float Sd[64][65];  // +1 pad: conflict-free col reads
  __shared__ float Se[64][65];
  const int k = blockIdx.x;
  const int dblk = dtab[blockIdx.y], eblk = etab[blockIdx.y];
  const float wgt = (dblk == eblk) ? 0.5f : 1.0f;
  const int tid = threadIdx.x;
  const int row = tid >> 2;         // 0..63
  const int c0 = (tid & 3) * 16;    // 0,16,32,48
  const size_t base = (size_t)k * D_N * D_N;
  const float* pd = Sigma + base + (size_t)(dblk * 64 + row) * D_N + eblk * 64 + c0;
  const float* pe = Sigma + base + (size_t)(eblk * 64 + row) * D_N + dblk * 64 + c0;
#pragma unroll
  for (int j = 0; j < 4; ++j) {
    *(float4*)&Sd[row][c0 + j * 4] = *(const float4*)(pd + j * 4);
    *(float4*)&Se[row][c0 + j * 4] = *(const float4*)(pe + j * 4);
  }
  __syncthreads();
  ushort h[16], l[16];
#pragma unroll
  for (int i = 0; i < 16; ++i) {
    const float t = (Sd[row][c0 + i] + Se[c0 + i][row]) * wgt;
    h[i] = bf16_rne(t);
    l[i] = bf16_rne(t - bf16_f32(h[i]));
  }
  const size_t rowbase = base + (size_t)(dblk * 64 + row) * D_N + eblk * 64 + c0;
  *(uint4*)(Th + rowbase) = *(uint4*)&h[0];
  *(uint4*)(Th + rowbase + 8) = *(uint4*)&h[8];
  *(uint4*)(Tl + rowbase) = *(uint4*)&l[0];
  *(uint4*)(Tl + rowbase + 8) = *(uint4*)&l[8];
}

// part[b][k][q] = sum_{d in q-block, e >= q*64} T_k[d][e] x[b][e] x[b][d].
// BLOCK-GRANULARITY SPLIT of the R9 structure (drain-overlap lever, the
// only mechanism that ever won big here -- R7/m114): block = 128 b-rows x
// TWO waves (128 thr), LDS 24 KB -> 6 blocks/CU co-resident (vs 3) and
// each chunk barrier syncs only 2 waves (less correlated stalling).
// PER-WAVE geometry is R9-verbatim (64b x 64d tile, 16 ds_reads + 48 MFMA
// per chunk -- the best measured FLOP/LDS ratio; NOT R12's halved tile).
// 2-barrier single-buffer loop, gload_lds w/ pre-swizzled source (0
// conflicts), 3-term bf16 split [XhTh|XlTh|XhTl], k-fastest XCD mapping,
// per-wave epilogue dot with exact f32 X -> identical part values.
__global__ __launch_bounds__(128, 6) void xsx_tri2w_kernel(
    const float* __restrict__ X,
    const ushort* __restrict__ Xh, const ushort* __restrict__ Xl,
    const ushort* __restrict__ Th, const ushort* __restrict__ Tl,
    float* __restrict__ part) {
  __shared__ __align__(16) ushort smem[12288];        // 24576 B exactly
  ushort(*A_h)[32] = (ushort(*)[32])(smem);           // [128][32]  8 KB
  ushort(*A_l)[32] = (ushort(*)[32])(smem + 4096);    //  8 KB
  ushort(*B_h)[32] = (ushort(*)[32])(smem + 8192);    // [64][32]   4 KB
  ushort(*B_l)[32] = (ushort(*)[32])(smem + 10240);   //  4 KB

  const int tid = threadIdx.x;
  const int lane = tid & 63;
  const int wid = tid >> 6;  // 0..1 : which 64 b-rows of the 128-row group
  const int lr = lane & 15;
  const int lk = lane >> 4;

  // 16384 blocks = 8 xcd * (4 q * 8 k * 64 bg); q in high bits -> long
  // (q=0) blocks dispatch first. Each XCD owns 8 k (T set L2-resident).
  const int bid = blockIdx.x;
  const int xcd = bid & 7;
  const int r = bid >> 3;        // 0..2047
  const int qd = r >> 9;         // 0..3 : d-block
  const int s = r & 511;
  const int kk = xcd * 8 + (s & 7);
  const int bg = s >> 3;         // 0..63 : 128-row b-group
  const int bbase = bg * 128;

  // Staging source swizzle (both-sides, R7-verified): lane l writes LDS phys
  // chunk (l&3) of row grp+(l>>2); reads logical chunk (l&3)^((l>>3)&3).
  const int srow = lane >> 2;
  const int sc = ((lane & 3) ^ ((lane >> 3) & 3)) * 8;
  const int rdc = (lk ^ ((lr >> 1) & 3)) * 8;  // ds_read side

  f32x4 acc[4][4];
#pragma unroll
  for (int mi = 0; mi < 4; ++mi)
#pragma unroll
    for (int ni = 0; ni < 4; ++ni) acc[mi][ni] = (f32x4){0.f, 0.f, 0.f, 0.f};

  const size_t a0 = (size_t)(bbase + wid * 64 + srow) * D_N + sc;
  const size_t b0g = (size_t)kk * (D_N * D_N) +
                     (size_t)(qd * 64 + wid * 32 + srow) * D_N + sc;

  const int nch = 2 * (4 - qd);
  for (int c = 0; c < nch; ++c) {
    const int e0 = qd * 64 + c * 32;
    __syncthreads();  // prior compute done before overwrite (2-wave sync)
    // A: wave stages its own 64 rows (4 groups of 16), hi+lo.
#pragma unroll
    for (int i = 0; i < 4; ++i) {
      gload_lds16(Xh + a0 + i * 16 * D_N + e0, &A_h[wid * 64 + i * 16][0]);
      gload_lds16(Xl + a0 + i * 16 * D_N + e0, &A_l[wid * 64 + i * 16][0]);
    }
    // B (T rows d in q-block, 64 rows): wave stages 32 rows, hi+lo.
#pragma unroll
    for (int i = 0; i < 2; ++i) {
      gload_lds16(Th + b0g + i * 16 * D_N + e0, &B_h[wid * 32 + i * 16][0]);
      gload_lds16(Tl + b0g + i * 16 * D_N + e0, &B_l[wid * 32 + i * 16][0]);
    }
    __syncthreads();  // compiler drains vmcnt(0) before barrier

    bf16x8 ah[4], al[4];
#pragma unroll
    for (int mi = 0; mi < 4; ++mi) {
      ah[mi] = *(const bf16x8*)&A_h[wid * 64 + mi * 16 + lr][rdc];
      al[mi] = *(const bf16x8*)&A_l[wid * 64 + mi * 16 + lr][rdc];
    }
#pragma unroll
    for (int ni = 0; ni < 4; ++ni) {
      const bf16x8 bh = *(const bf16x8*)&B_h[ni * 16 + lr][rdc];
      const bf16x8 bl = *(const bf16x8*)&B_l[ni * 16 + lr][rdc];
#pragma unroll
      for (int mi = 0; mi < 4; ++mi)
        acc[mi][ni] = __builtin_amdgcn_mfma_f32_16x16x32_bf16(
            ah[mi], bh, acc[mi][ni], 0, 0, 0);
#pragma unroll
      for (int mi = 0; mi < 4; ++mi)
        acc[mi][ni] = __builtin_amdgcn_mfma_f32_16x16x32_bf16(
            al[mi], bh, acc[mi][ni], 0, 0, 0);
#pragma unroll
      for (int mi = 0; mi < 4; ++mi)
        acc[mi][ni] = __builtin_amdgcn_mfma_f32_16x16x32_bf16(
            ah[mi], bl, acc[mi][ni], 0, 0, 0);
    }
  }

  // Per-wave epilogue (wave owns distinct b-rows; no cross-wave reduce).
  // C/D layout (verified): col = lane&15 (d), row = (lane>>4)*4 + jj (b).
#pragma unroll
  for (int mi = 0; mi < 4; ++mi) {
#pragma unroll
    for (int jj = 0; jj < 4; ++jj) {
      const int brow = bbase + wid * 64 + mi * 16 + lk * 4 + jj;
      const float* xr = X + (size_t)brow * D_N + qd * 64 + lr;
      float p = 0.f;
#pragma unroll
      for (int ni = 0; ni < 4; ++ni) p = fmaf(acc[mi][ni][jj], xr[ni * 16], p);
      p += __shfl_xor(p, 1);
      p += __shfl_xor(p, 2);
      p += __shfl_xor(p, 4);
      p += __shfl_xor(p, 8);
      if (lr == 0) part[((size_t)brow * K_N + kk) * 4 + qd] = p;
    }
  }
}

// Fallback (small ws): in-block convert, 128-tile (round-1 verified path).
__global__ __launch_bounds__(512, 2) void xsx_fallback(
    const float* __restrict__ X, const float* __restrict__ Sigma,
    float* __restrict__ xsx) {
  constexpr int BM = 128, KT = 32;
  __shared__ __align__(16) ushort Ah[BM][KT];
  __shared__ __align__(16) ushort Al[BM][KT];
  __shared__ __align__(16) ushort Bh[D_N][KT];
  __shared__ __align__(16) ushort Bl[D_N][KT];
  __shared__ float red[4][BM];

  const int tid = threadIdx.x;
  const int lane = tid & 63;
  const int wid = tid >> 6;
  const int wm = wid >> 2;
  const int wn = wid & 3;
  const int lr = lane & 15;
  const int lk = lane >> 4;

  const int b0 = blockIdx.x * BM;
  const int kk = blockIdx.y;
  const size_t soff = (size_t)kk * D_N * D_N;

  f32x4 acc[4][4];
#pragma unroll
  for (int mi = 0; mi < 4; ++mi)
#pragma unroll
    for (int ni = 0; ni < 4; ++ni) acc[mi][ni] = (f32x4){0.f, 0.f, 0.f, 0.f};

  for (int ec = 0; ec < D_N / KT; ++ec) {
    const int e0 = ec * KT;
    __syncthreads();
#pragma unroll
    for (int r = 0; r < 2; ++r) {
      const int i = tid + 512 * r;
      const int row = i >> 3, c4 = (i & 7) * 4;
      const float4 v = *(const float4*)(X + (size_t)(b0 + row) * D_N + e0 + c4);
      ushort4 h, l;
      h.x = bf16_rne(v.x); l.x = bf16_rne(v.x - bf16_f32(h.x));
      h.y = bf16_rne(v.y); l.y = bf16_rne(v.y - bf16_f32(h.y));
      h.z = bf16_rne(v.z); l.z = bf16_rne(v.z - bf16_f32(h.z));
      h.w = bf16_rne(v.w); l.w = bf16_rne(v.w - bf16_f32(h.w));
      *(ushort4*)&Ah[row][c4] = h;
      *(ushort4*)&Al[row][c4] = l;
    }
#pragma unroll
    for (int r = 0; r < 4; ++r) {
      const int i = tid + 512 * r;
      const int d = i >> 3, c4 = (i & 7) * 4;
      const float4 v = *(const float4*)(Sigma + soff + (size_t)d * D_N + e0 + c4);
      ushort4 h, l;
      h.x = bf16_rne(v.x); l.x = bf16_rne(v.x - bf16_f32(h.x));
      h.y = bf16_rne(v.y); l.y = bf16_rne(v.y - bf16_f32(h.y));
      h.z = bf16_rne(v.z); l.z = bf16_rne(v.z - bf16_f32(h.z));
      h.w = bf16_rne(v.w); l.w = bf16_rne(v.w - bf16_f32(h.w));
      *(ushort4*)&Bh[d][c4] = h;
      *(ushort4*)&Bl[d][c4] = l;
    }
    __syncthreads();

    bf16x8 ah[4], al[4];
#pragma unroll
    for (int mi = 0; mi < 4; ++mi) {
      ah[mi] = *(const bf16x8*)&Ah[wm * 64 + mi * 16 + lr][lk * 8];
      al[mi] = *(const bf16x8*)&Al[wm * 64 + mi * 16 + lr][lk * 8];
    }
#pragma unroll
    for (int ni = 0; ni < 4; ++ni) {
      const bf16x8 bh = *(const bf16x8*)&Bh[wn * 64 + ni * 16 + lr][lk * 8];
      const bf16x8 bl = *(const bf16x8*)&Bl[wn * 64 + ni * 16 + lr][lk * 8];
#pragma unroll
      for (int mi = 0; mi < 4; ++mi) {
        acc[mi][ni] = __builtin_amdgcn_mfma_f32_16x16x32_bf16(ah[mi], bh, acc[mi][ni], 0, 0, 0);
        acc[mi][ni] = __builtin_amdgcn_mfma_f32_16x16x32_bf16(al[mi], bh, acc[mi][ni], 0, 0, 0);
        acc[mi][ni] = __builtin_amdgcn_mfma_f32_16x16x32_bf16(ah[mi], bl, acc[mi][ni], 0, 0, 0);
      }
    }
  }

  float p[4][4];
#pragma unroll
  for (int mi = 0; mi < 4; ++mi)
#pragma unroll
    for (int jj = 0; jj < 4; ++jj) p[mi][jj] = 0.f;
#pragma unroll
  for (int mi = 0; mi < 4; ++mi) {
#pragma unroll
    for (int jj = 0; jj < 4; ++jj) {
      const int brow = b0 + wm * 64 + mi * 16 + lk * 4 + jj;
      const float* xr = X + (size_t)brow * D_N + wn * 64 + lr;
#pragma unroll
      for (int ni = 0; ni < 4; ++ni)
        p[mi][jj] = fmaf(acc[mi][ni][jj], xr[ni * 16], p[mi][jj]);
    }
  }
#pragma unroll
  for (int mi = 0; mi < 4; ++mi)
#pragma unroll
    for (int jj = 0; jj < 4; ++jj) {
      float v = p[mi][jj];
      v += __shfl_xor(v, 1);
      v += __shfl_xor(v, 2);
      v += __shfl_xor(v, 4);
      v += __shfl_xor(v, 8);
      p[mi][jj] = v;
    }
  if (lr == 0) {
#pragma unroll
    for (int mi = 0; mi < 4; ++mi)
#pragma unroll
      for (int jj = 0; jj < 4; ++jj)
        red[wn][wm * 64 + mi * 16 + lk * 4 + jj] = p[mi][jj];
  }
  __syncthreads();
  if (tid < BM) {
    const float s = red[0][tid] + red[1][tid] + red[2][tid] + red[3][tid];
    xsx[(size_t)(b0 + tid) * K_N + kk] = s;
  }
}

// One wave per batch row b; lane k owns class k in [0,64). (R9 tail.)
// nparts==4: sum part[b][k][0..3] in fixed order.
__global__ __launch_bounds__(256) void loss_kernel(
    const float* __restrict__ X, const int* __restrict__ y,
    const float* __restrict__ mu, const int* __restrict__ loss_type,
    const float* __restrict__ xsx, float* __restrict__ out, int nparts) {
  __shared__ float mu_s[D_N * K_N];  // 64 KB
  __shared__ float x_s[4][D_N];      //  4 KB
  const int tid = threadIdx.x;
  const int wid = tid >> 6;
  const int lane = tid & 63;
  const int b = blockIdx.x * 4 + wid;

  for (int i = tid; i < D_N * K_N / 4; i += 256)
    ((float4*)mu_s)[i] = ((const float4*)mu)[i];
  ((float4*)&x_s[wid][0])[lane] = ((const float4*)(X + (size_t)b * D_N))[lane];
  __syncthreads();

  const int yb = y[b];
  const int lt = loss_type[0];

  float logit = 0.f;
#pragma unroll 8
  for (int d = 0; d < D_N; ++d)
    logit = fmaf(x_s[wid][d], mu_s[d * K_N + lane], logit);

  float term;
  if (lt == 1) {
    float xv;
    if (nparts == 4) {
      const float4 pv = *(const float4*)(xsx + ((size_t)b * K_N + lane) * 4);
      xv = ((pv.x + pv.y) + pv.z) + pv.w;
    } else {
      xv = xsx[(size_t)b * K_N + lane];
    }
    const float psi = sqrtf(fmaxf(xv + logit * logit, 0.f));
    const float bk = (lane <= yb) ? 1.f : 0.f;
    const float kap = ((lane == yb) ? 1.f : 0.f) - 0.5f * bk;
    // psi/2 - softplus(psi) = -psi/2 - log1p(exp(-psi)) for psi >= 0
    term = logit * kap + bk * (-0.5f * psi - log1pf(expf(-psi)));
  } else {
    const float sp = (logit > 0.f) ? (logit + log1pf(expf(-logit)))
                                   : log1pf(expf(logit));
    term = ((lane == yb) ? logit : 0.f) - ((lane <= yb) ? sp : 0.f);
  }
#pragma unroll
  for (int s = 1; s < 64; s <<= 1) term += __shfl_xor(term, s);
  if (lane == 0) out[b] = -term;
}

extern "C" void kernel_launch(void* const* d_in, const int* in_sizes, int n_in,
                              void* d_out, int out_size, void* d_ws, size_t ws_size,
                              hipStream_t stream) {
  const float* X = (const float*)d_in[0];
  const int* y = (const int*)d_in[1];
  const float* mu = (const float*)d_in[2];
  const float* Sigma = (const float*)d_in[3];
  const int* lt = (const int*)d_in[4];
  float* out = (float*)d_out;

  const size_t XN = (size_t)B_N * D_N;        // 2,097,152 elems
  const size_t SN = (size_t)K_N * D_N * D_N;  // 4,194,304 elems
  const size_t xh_off = 0;
  const size_t xl_off = xh_off + XN * 2;
  const size_t th_off = xl_off + XN * 2;
  const size_t tl_off = th_off + SN * 2;
  const size_t part_off = tl_off + SN * 2;
  const size_t need = part_off + (size_t)B_N * K_N * 4 * 4;  // 32 MiB

  char* w = (char*)d_ws;
  if (ws_size >= need) {
    ushort* Xh = (ushort*)(w + xh_off);
    ushort* Xl = (ushort*)(w + xl_off);
    ushort* Th = (ushort*)(w + th_off);
    ushort* Tl = (ushort*)(w + tl_off);
    float* part = (float*)(w + part_off);
    hipLaunchKernelGGL(convert_kernel, dim3(1024), dim3(256), 0, stream,
                       X, Xh, Xl, (int)(XN / 4));
    hipLaunchKernelGGL(convert_T_kernel, dim3(64, 10), dim3(256), 0, stream,
                       Sigma, Th, Tl);
    hipLaunchKernelGGL(xsx_tri2w_kernel, dim3(16384), dim3(128), 0, stream,
                       X, Xh, Xl, Th, Tl, part);
    hipLaunchKernelGGL(loss_kernel, dim3(B_N / 4), dim3(256), 0, stream,
                       X, y, mu, lt, part, out, 4);
  } else {
    float* xsx = (float*)w;  // needs 2 MB
    hipLaunchKernelGGL(xsx_fallback, dim3(B_N / 128, K_N), dim3(512), 0, stream,
                       X, Sigma, xsx);
    hipLaunchKernelGGL(loss_kernel, dim3(B_N / 4), dim3(256), 0, stream,
                       X, y, mu, lt, xsx, out, 1);
  }
}

// Round 17
// 193.661 us; speedup vs baseline: 1.1406x; 1.1406x over previous
//
#include <hip/hip_runtime.h>

typedef __attribute__((ext_vector_type(8))) short bf16x8;
typedef __attribute__((ext_vector_type(4))) float f32x4;

#define B_N 8192
#define D_N 256
#define K_N 64

__device__ __forceinline__ unsigned short bf16_rne(float f) {
  unsigned u = __builtin_bit_cast(unsigned, f);
  u += 0x7fffu + ((u >> 16) & 1u);
  return (unsigned short)(u >> 16);
}
__device__ __forceinline__ float bf16_f32(unsigned short h) {
  return __builtin_bit_cast(float, (unsigned)h << 16);
}

// DMA 16B/lane global->LDS. LDS dest: wave-uniform base + lane*16 (linear).
__device__ __forceinline__ void gload_lds16(const void* g, void* l) {
  __builtin_amdgcn_global_load_lds(
      (const __attribute__((address_space(1))) unsigned int*)g,
      (__attribute__((address_space(3))) unsigned int*)l, 16, 0, 0);
}

// One-time f32 -> bf16 (hi) + bf16 (residual lo) split (for X).
__global__ void convert_kernel(const float* __restrict__ src,
                               ushort* __restrict__ hi, ushort* __restrict__ lo,
                               int n4) {
  int idx = blockIdx.x * blockDim.x + threadIdx.x;
  int stride = gridDim.x * blockDim.x;
  for (int i = idx; i < n4; i += stride) {
    float4 v = ((const float4*)src)[i];
    ushort4 h, l;
    h.x = bf16_rne(v.x); l.x = bf16_rne(v.x - bf16_f32(h.x));
    h.y = bf16_rne(v.y); l.y = bf16_rne(v.y - bf16_f32(h.y));
    h.z = bf16_rne(v.z); l.z = bf16_rne(v.z - bf16_f32(h.z));
    h.w = bf16_rne(v.w); l.w = bf16_rne(v.w - bf16_f32(h.w));
    ((ushort4*)hi)[i] = h;
    ((ushort4*)lo)[i] = l;
  }
}

// Symmetrize-and-fold: x^T S x == x^T Sym x (Sym=(S+S^T)/2) EXACTLY for any
// S. T[d][e] = Sym (same 64-block), 2*Sym (e-block > d-block). LDS
// tile-transpose (R15-measured): both 64x64 tiles load coalesced into
// padded LDS; symmetrize reads LDS (no strided 4B gathers).
__global__ void convert_T_kernel(const float* __restrict__ Sigma,
                                 ushort* __restrict__ Th,
                                 ushort* __restrict__ Tl) {
  const int dtab[10] = {0, 0, 0, 0, 1, 1, 1, 2, 2, 3};
  const int etab[10] = {0, 1, 2, 3, 1, 2, 3, 2, 3, 3};
  __shared__ float Sd[64][65];  // +1 pad: conflict-free col reads
  __shared__ float Se[64][65];
  const int k = blockIdx.x;
  const int dblk = dtab[blockIdx.y], eblk = etab[blockIdx.y];
  const float wgt = (dblk == eblk) ? 0.5f : 1.0f;
  const int tid = threadIdx.x;
  const int row = tid >> 2;         // 0..63
  const int c0 = (tid & 3) * 16;    // 0,16,32,48
  const size_t base = (size_t)k * D_N * D_N;
  const float* pd = Sigma + base + (size_t)(dblk * 64 + row) * D_N + eblk * 64 + c0;
  const float* pe = Sigma + base + (size_t)(eblk * 64 + row) * D_N + dblk * 64 + c0;
#pragma unroll
  for (int j = 0; j < 4; ++j) {
    *(float4*)&Sd[row][c0 + j * 4] = *(const float4*)(pd + j * 4);
    *(float4*)&Se[row][c0 + j * 4] = *(const float4*)(pe + j * 4);
  }
  __syncthreads();
  ushort h[16], l[16];
#pragma unroll
  for (int i = 0; i < 16; ++i) {
    const float t = (Sd[row][c0 + i] + Se[c0 + i][row]) * wgt;
    h[i] = bf16_rne(t);
    l[i] = bf16_rne(t - bf16_f32(h[i]));
  }
  const size_t rowbase = base + (size_t)(dblk * 64 + row) * D_N + eblk * 64 + c0;
  *(uint4*)(Th + rowbase) = *(uint4*)&h[0];
  *(uint4*)(Th + rowbase + 8) = *(uint4*)&h[8];
  *(uint4*)(Tl + rowbase) = *(uint4*)&l[0];
  *(uint4*)(Tl + rowbase + 8) = *(uint4*)&l[8];
}

// part[b][k][q] = sum_{d in q-block, e >= q*64} T_k[d][e] x[b][e] x[b][d].
// R9-VERBATIM, (256,3) -- measured best across 16 rounds (167 us, MfmaUtil
// 33, FETCH 120 MB, 0 conflicts, 0 spill). Block = (xcd-k, q, 256-row
// b-group); 4 waves x 64 b-rows; wave tile 64b x 64d; contraction
// 2*(4-q) chunks of 32 (long blocks dispatch first). 2-barrier
// single-buffer loop, gload_lds w/ pre-swizzled source, 3-term bf16 split
// [XhTh|XlTh|XhTl], per-wave epilogue dot with exact f32 X. Falsified
// alternatives: phased/counted-vmcnt scheds (R3,R4), A-direct (R10,R13),
// forced occupancy (R8,R11,R15), smaller acc (R12), 2-wave blocks (R16).
__global__ __launch_bounds__(256, 3) void xsx_tri_kernel(
    const float* __restrict__ X,
    const ushort* __restrict__ Xh, const ushort* __restrict__ Xl,
    const ushort* __restrict__ Th, const ushort* __restrict__ Tl,
    float* __restrict__ part) {
  __shared__ __align__(16) ushort smem[20480];        // 40960 B exactly
  ushort(*A_h)[32] = (ushort(*)[32])(smem);           // [256][32] 16 KB
  ushort(*A_l)[32] = (ushort(*)[32])(smem + 8192);    // 16 KB
  ushort(*B_h)[32] = (ushort(*)[32])(smem + 16384);   // [64][32]   4 KB
  ushort(*B_l)[32] = (ushort(*)[32])(smem + 18432);   //  4 KB

  const int tid = threadIdx.x;
  const int lane = tid & 63;
  const int wid = tid >> 6;  // 0..3 : which 64 b-rows of the 256-row group
  const int lr = lane & 15;
  const int lk = lane >> 4;

  // 8192 blocks = 8 xcd * (4 q * 8 k * 32 bg); q in high bits -> long
  // (q=0) blocks dispatch first. Each XCD owns 8 k (T set L2-resident).
  const int bid = blockIdx.x;
  const int xcd = bid & 7;
  const int r = bid >> 3;        // 0..1023
  const int qd = r >> 8;         // 0..3 : d-block
  const int s = r & 255;
  const int kk = xcd * 8 + (s & 7);
  const int bg = s >> 3;         // 0..31 : 256-row b-group
  const int bbase = bg * 256;

  // Staging source swizzle (both-sides, R7-verified): lane l writes LDS phys
  // chunk (l&3) of row grp+(l>>2); reads logical chunk (l&3)^((l>>3)&3).
  const int srow = lane >> 2;
  const int sc = ((lane & 3) ^ ((lane >> 3) & 3)) * 8;
  const int rdc = (lk ^ ((lr >> 1) & 3)) * 8;  // ds_read side

  f32x4 acc[4][4];
#pragma unroll
  for (int mi = 0; mi < 4; ++mi)
#pragma unroll
    for (int ni = 0; ni < 4; ++ni) acc[mi][ni] = (f32x4){0.f, 0.f, 0.f, 0.f};

  const size_t a0 = (size_t)(bbase + wid * 64 + srow) * D_N + sc;
  const size_t b0g = (size_t)kk * (D_N * D_N) +
                     (size_t)(qd * 64 + wid * 16 + srow) * D_N + sc;

  const int nch = 2 * (4 - qd);
  for (int c = 0; c < nch; ++c) {
    const int e0 = qd * 64 + c * 32;
    __syncthreads();  // prior compute done before overwrite
    // A: wave stages its own 64 rows (4 groups of 16), hi+lo.
#pragma unroll
    for (int i = 0; i < 4; ++i) {
      gload_lds16(Xh + a0 + i * 16 * D_N + e0, &A_h[wid * 64 + i * 16][0]);
      gload_lds16(Xl + a0 + i * 16 * D_N + e0, &A_l[wid * 64 + i * 16][0]);
    }
    // B (T rows d in q-block): wave stages 16 rows, hi+lo.
    gload_lds16(Th + b0g + e0, &B_h[wid * 16][0]);
    gload_lds16(Tl + b0g + e0, &B_l[wid * 16][0]);
    __syncthreads();  // compiler drains vmcnt(0) before barrier

    bf16x8 ah[4], al[4];
#pragma unroll
    for (int mi = 0; mi < 4; ++mi) {
      ah[mi] = *(const bf16x8*)&A_h[wid * 64 + mi * 16 + lr][rdc];
      al[mi] = *(const bf16x8*)&A_l[wid * 64 + mi * 16 + lr][rdc];
    }
#pragma unroll
    for (int ni = 0; ni < 4; ++ni) {
      const bf16x8 bh = *(const bf16x8*)&B_h[ni * 16 + lr][rdc];
      const bf16x8 bl = *(const bf16x8*)&B_l[ni * 16 + lr][rdc];
#pragma unroll
      for (int mi = 0; mi < 4; ++mi)
        acc[mi][ni] = __builtin_amdgcn_mfma_f32_16x16x32_bf16(
            ah[mi], bh, acc[mi][ni], 0, 0, 0);
#pragma unroll
      for (int mi = 0; mi < 4; ++mi)
        acc[mi][ni] = __builtin_amdgcn_mfma_f32_16x16x32_bf16(
            al[mi], bh, acc[mi][ni], 0, 0, 0);
#pragma unroll
      for (int mi = 0; mi < 4; ++mi)
        acc[mi][ni] = __builtin_amdgcn_mfma_f32_16x16x32_bf16(
            ah[mi], bl, acc[mi][ni], 0, 0, 0);
    }
  }

  // Per-wave epilogue (wave owns distinct b-rows; no cross-wave reduce).
  // C/D layout (verified): col = lane&15 (d), row = (lane>>4)*4 + jj (b).
#pragma unroll
  for (int mi = 0; mi < 4; ++mi) {
#pragma unroll
    for (int jj = 0; jj < 4; ++jj) {
      const int brow = bbase + wid * 64 + mi * 16 + lk * 4 + jj;
      const float* xr = X + (size_t)brow * D_N + qd * 64 + lr;
      float p = 0.f;
#pragma unroll
      for (int ni = 0; ni < 4; ++ni) p = fmaf(acc[mi][ni][jj], xr[ni * 16], p);
      p += __shfl_xor(p, 1);
      p += __shfl_xor(p, 2);
      p += __shfl_xor(p, 4);
      p += __shfl_xor(p, 8);
      if (lr == 0) part[((size_t)brow * K_N + kk) * 4 + qd] = p;
    }
  }
}

// Fallback (small ws): in-block convert, 128-tile (round-1 verified path).
__global__ __launch_bounds__(512, 2) void xsx_fallback(
    const float* __restrict__ X, const float* __restrict__ Sigma,
    float* __restrict__ xsx) {
  constexpr int BM = 128, KT = 32;
  __shared__ __align__(16) ushort Ah[BM][KT];
  __shared__ __align__(16) ushort Al[BM][KT];
  __shared__ __align__(16) ushort Bh[D_N][KT];
  __shared__ __align__(16) ushort Bl[D_N][KT];
  __shared__ float red[4][BM];

  const int tid = threadIdx.x;
  const int lane = tid & 63;
  const int wid = tid >> 6;
  const int wm = wid >> 2;
  const int wn = wid & 3;
  const int lr = lane & 15;
  const int lk = lane >> 4;

  const int b0 = blockIdx.x * BM;
  const int kk = blockIdx.y;
  const size_t soff = (size_t)kk * D_N * D_N;

  f32x4 acc[4][4];
#pragma unroll
  for (int mi = 0; mi < 4; ++mi)
#pragma unroll
    for (int ni = 0; ni < 4; ++ni) acc[mi][ni] = (f32x4){0.f, 0.f, 0.f, 0.f};

  for (int ec = 0; ec < D_N / KT; ++ec) {
    const int e0 = ec * KT;
    __syncthreads();
#pragma unroll
    for (int r = 0; r < 2; ++r) {
      const int i = tid + 512 * r;
      const int row = i >> 3, c4 = (i & 7) * 4;
      const float4 v = *(const float4*)(X + (size_t)(b0 + row) * D_N + e0 + c4);
      ushort4 h, l;
      h.x = bf16_rne(v.x); l.x = bf16_rne(v.x - bf16_f32(h.x));
      h.y = bf16_rne(v.y); l.y = bf16_rne(v.y - bf16_f32(h.y));
      h.z = bf16_rne(v.z); l.z = bf16_rne(v.z - bf16_f32(h.z));
      h.w = bf16_rne(v.w); l.w = bf16_rne(v.w - bf16_f32(h.w));
      *(ushort4*)&Ah[row][c4] = h;
      *(ushort4*)&Al[row][c4] = l;
    }
#pragma unroll
    for (int r = 0; r < 4; ++r) {
      const int i = tid + 512 * r;
      const int d = i >> 3, c4 = (i & 7) * 4;
      const float4 v = *(const float4*)(Sigma + soff + (size_t)d * D_N + e0 + c4);
      ushort4 h, l;
      h.x = bf16_rne(v.x); l.x = bf16_rne(v.x - bf16_f32(h.x));
      h.y = bf16_rne(v.y); l.y = bf16_rne(v.y - bf16_f32(h.y));
      h.z = bf16_rne(v.z); l.z = bf16_rne(v.z - bf16_f32(h.z));
      h.w = bf16_rne(v.w); l.w = bf16_rne(v.w - bf16_f32(h.w));
      *(ushort4*)&Bh[d][c4] = h;
      *(ushort4*)&Bl[d][c4] = l;
    }
    __syncthreads();

    bf16x8 ah[4], al[4];
#pragma unroll
    for (int mi = 0; mi < 4; ++mi) {
      ah[mi] = *(const bf16x8*)&Ah[wm * 64 + mi * 16 + lr][lk * 8];
      al[mi] = *(const bf16x8*)&Al[wm * 64 + mi * 16 + lr][lk * 8];
    }
#pragma unroll
    for (int ni = 0; ni < 4; ++ni) {
      const bf16x8 bh = *(const bf16x8*)&Bh[wn * 64 + ni * 16 + lr][lk * 8];
      const bf16x8 bl = *(const bf16x8*)&Bl[wn * 64 + ni * 16 + lr][lk * 8];
#pragma unroll
      for (int mi = 0; mi < 4; ++mi) {
        acc[mi][ni] = __builtin_amdgcn_mfma_f32_16x16x32_bf16(ah[mi], bh, acc[mi][ni], 0, 0, 0);
        acc[mi][ni] = __builtin_amdgcn_mfma_f32_16x16x32_bf16(al[mi], bh, acc[mi][ni], 0, 0, 0);
        acc[mi][ni] = __builtin_amdgcn_mfma_f32_16x16x32_bf16(ah[mi], bl, acc[mi][ni], 0, 0, 0);
      }
    }
  }

  float p[4][4];
#pragma unroll
  for (int mi = 0; mi < 4; ++mi)
#pragma unroll
    for (int jj = 0; jj < 4; ++jj) p[mi][jj] = 0.f;
#pragma unroll
  for (int mi = 0; mi < 4; ++mi) {
#pragma unroll
    for (int jj = 0; jj < 4; ++jj) {
      const int brow = b0 + wm * 64 + mi * 16 + lk * 4 + jj;
      const float* xr = X + (size_t)brow * D_N + wn * 64 + lr;
#pragma unroll
      for (int ni = 0; ni < 4; ++ni)
        p[mi][jj] = fmaf(acc[mi][ni][jj], xr[ni * 16], p[mi][jj]);
    }
  }
#pragma unroll
  for (int mi = 0; mi < 4; ++mi)
#pragma unroll
    for (int jj = 0; jj < 4; ++jj) {
      float v = p[mi][jj];
      v += __shfl_xor(v, 1);
      v += __shfl_xor(v, 2);
      v += __shfl_xor(v, 4);
      v += __shfl_xor(v, 8);
      p[mi][jj] = v;
    }
  if (lr == 0) {
#pragma unroll
    for (int mi = 0; mi < 4; ++mi)
#pragma unroll
      for (int jj = 0; jj < 4; ++jj)
        red[wn][wm * 64 + mi * 16 + lk * 4 + jj] = p[mi][jj];
  }
  __syncthreads();
  if (tid < BM) {
    const float s = red[0][tid] + red[1][tid] + red[2][tid] + red[3][tid];
    xsx[(size_t)(b0 + tid) * K_N + kk] = s;
  }
}

// One wave per batch row b; lane k owns class k in [0,64). (R9 tail --
// measured fastest loss variant.) nparts==4: sum part[b][k][0..3].
__global__ __launch_bounds__(256) void loss_kernel(
    const float* __restrict__ X, const int* __restrict__ y,
    const float* __restrict__ mu, const int* __restrict__ loss_type,
    const float* __restrict__ xsx, float* __restrict__ out, int nparts) {
  __shared__ float mu_s[D_N * K_N];  // 64 KB
  __shared__ float x_s[4][D_N];      //  4 KB
  const int tid = threadIdx.x;
  const int wid = tid >> 6;
  const int lane = tid & 63;
  const int b = blockIdx.x * 4 + wid;

  for (int i = tid; i < D_N * K_N / 4; i += 256)
    ((float4*)mu_s)[i] = ((const float4*)mu)[i];
  ((float4*)&x_s[wid][0])[lane] = ((const float4*)(X + (size_t)b * D_N))[lane];
  __syncthreads();

  const int yb = y[b];
  const int lt = loss_type[0];

  float logit = 0.f;
#pragma unroll 8
  for (int d = 0; d < D_N; ++d)
    logit = fmaf(x_s[wid][d], mu_s[d * K_N + lane], logit);

  float term;
  if (lt == 1) {
    float xv;
    if (nparts == 4) {
      const float4 pv = *(const float4*)(xsx + ((size_t)b * K_N + lane) * 4);
      xv = ((pv.x + pv.y) + pv.z) + pv.w;
    } else {
      xv = xsx[(size_t)b * K_N + lane];
    }
    const float psi = sqrtf(fmaxf(xv + logit * logit, 0.f));
    const float bk = (lane <= yb) ? 1.f : 0.f;
    const float kap = ((lane == yb) ? 1.f : 0.f) - 0.5f * bk;
    // psi/2 - softplus(psi) = -psi/2 - log1p(exp(-psi)) for psi >= 0
    term = logit * kap + bk * (-0.5f * psi - log1pf(expf(-psi)));
  } else {
    const float sp = (logit > 0.f) ? (logit + log1pf(expf(-logit)))
                                   : log1pf(expf(logit));
    term = ((lane == yb) ? logit : 0.f) - ((lane <= yb) ? sp : 0.f);
  }
#pragma unroll
  for (int s = 1; s < 64; s <<= 1) term += __shfl_xor(term, s);
  if (lane == 0) out[b] = -term;
}

extern "C" void kernel_launch(void* const* d_in, const int* in_sizes, int n_in,
                              void* d_out, int out_size, void* d_ws, size_t ws_size,
                              hipStream_t stream) {
  const float* X = (const float*)d_in[0];
  const int* y = (const int*)d_in[1];
  const float* mu = (const float*)d_in[2];
  const float* Sigma = (const float*)d_in[3];
  const int* lt = (const int*)d_in[4];
  float* out = (float*)d_out;

  const size_t XN = (size_t)B_N * D_N;        // 2,097,152 elems
  const size_t SN = (size_t)K_N * D_N * D_N;  // 4,194,304 elems
  const size_t xh_off = 0;
  const size_t xl_off = xh_off + XN * 2;
  const size_t th_off = xl_off + XN * 2;
  const size_t tl_off = th_off + SN * 2;
  const size_t part_off = tl_off + SN * 2;
  const size_t need = part_off + (size_t)B_N * K_N * 4 * 4;  // 32 MiB

  char* w = (char*)d_ws;
  if (ws_size >= need) {
    ushort* Xh = (ushort*)(w + xh_off);
    ushort* Xl = (ushort*)(w + xl_off);
    ushort* Th = (ushort*)(w + th_off);
    ushort* Tl = (ushort*)(w + tl_off);
    float* part = (float*)(w + part_off);
    hipLaunchKernelGGL(convert_kernel, dim3(1024), dim3(256), 0, stream,
                       X, Xh, Xl, (int)(XN / 4));
    hipLaunchKernelGGL(convert_T_kernel, dim3(64, 10), dim3(256), 0, stream,
                       Sigma, Th, Tl);
    hipLaunchKernelGGL(xsx_tri_kernel, dim3(8192), dim3(256), 0, stream,
                       X, Xh, Xl, Th, Tl, part);
    hipLaunchKernelGGL(loss_kernel, dim3(B_N / 4), dim3(256), 0, stream,
                       X, y, mu, lt, part, out, 4);
  } else {
    float* xsx = (float*)w;  // needs 2 MB
    hipLaunchKernelGGL(xsx_fallback, dim3(B_N / 128, K_N), dim3(512), 0, stream,
                       X, Sigma, xsx);
    hipLaunchKernelGGL(loss_kernel, dim3(B_N / 4), dim3(256), 0, stream,
                       X, y, mu, lt, xsx, out, 1);
  }
}